// Round 19
// baseline (151.385 us; speedup 1.0000x reference)
//
#include <hip/hip_runtime.h>
#include <hip/hip_bf16.h>

#define FT 128
#define NH 8

typedef short bf16x8 __attribute__((ext_vector_type(8)));
typedef ushort u16x8 __attribute__((ext_vector_type(8)));
typedef float f32x4 __attribute__((ext_vector_type(4)));

__device__ __forceinline__ ushort f2bf(float f) {
  __hip_bfloat16 h = __float2bfloat16(f);
  return *reinterpret_cast<ushort*>(&h);
}
__device__ __forceinline__ float bf2f(ushort u) {
  return __uint_as_float(((unsigned)u) << 16);
}

// ---------------- setup: zero cnt + build Wt1/WtN (bf16 B-layout) + cb ----------------
__global__ void k_setup(const float* __restrict__ Wp, const float* __restrict__ bp,
                        const float* __restrict__ at2, ushort* __restrict__ Wt1,
                        ushort* __restrict__ WtN, float* __restrict__ cb,
                        int* __restrict__ cnt, int N) {
  int i = blockIdx.x * 256 + threadIdx.x;
  if (i < N) cnt[i] = 0;
  if (i < 128 * 128) {
    int c = i >> 7, k = i & 127;
    Wt1[i] = f2bf(Wp[(size_t)(128 + k) * 128 + c]);
  }
  if (i < 256 * 128) {
    int c = i >> 7, k = i & 127;
    float v = (c < 128) ? Wp[(size_t)k * 128 + c]
                        : Wp[(size_t)(256 + k) * 128 + (c - 128)];
    WtN[i] = f2bf(v);
  }
  if (i < NH) {
    float s = 0.0f;
    #pragma unroll
    for (int j = 0; j < 16; ++j) s += bp[i * 16 + j] * at2[i * 16 + j];
    cb[i] = s;
  }
}

// ---------------- COMBO: blocks [0,nbE) = histogram; blocks [nbE,..) = node GEMM ----------------
__global__ __launch_bounds__(256) void k_combo(
    const int* __restrict__ dst, int* __restrict__ cnt, int E, int nbE,
    const float* __restrict__ nft, const ushort* __restrict__ WtN,
    const float* __restrict__ at2, const float* __restrict__ Wa1,
    ushort* __restrict__ nsAll, float* __restrict__ c2n,
    float* __restrict__ a1n, int N)
{
  __shared__ ushort x[64][136];
  const int t = threadIdx.x;

  if ((int)blockIdx.x < nbE) {
    int e = blockIdx.x * 256 + t;
    if (e < E) atomicAdd(&cnt[dst[e]], 1);
    return;
  }

  const int n0 = (blockIdx.x - nbE) * 64;

  #pragma unroll
  for (int r = 0; r < 4; ++r) {
    int idx = r * 2048 + t * 8;
    int ei = idx >> 7, c = idx & 127;
    const float* xr = nft + (size_t)min(n0 + ei, N - 1) * FT + c;
    float4 u = *(const float4*)xr;
    float4 v = *(const float4*)(xr + 4);
    u16x8 pk;
    pk[0] = f2bf(u.x); pk[1] = f2bf(u.y); pk[2] = f2bf(u.z); pk[3] = f2bf(u.w);
    pk[4] = f2bf(v.x); pk[5] = f2bf(v.y); pk[6] = f2bf(v.z); pk[7] = f2bf(v.w);
    *(u16x8*)&x[ei][c] = pk;
  }
  __syncthreads();

  const int w  = t >> 6;
  const int l  = t & 63;
  const int lr = l & 15;
  const int lk = l >> 4;

  bf16x8 breg[4][4];
  const ushort* wb = WtN + ((size_t)(w * 64 + lr) * 128 + lk * 8);
  #pragma unroll
  for (int ntl = 0; ntl < 4; ++ntl)
    #pragma unroll
    for (int ks = 0; ks < 4; ++ks)
      breg[ks][ntl] = *(const bf16x8*)(wb + (size_t)ntl * 16 * 128 + ks * 32);

  f32x4 acc[4][4];
  #pragma unroll
  for (int m = 0; m < 4; ++m)
    #pragma unroll
    for (int ntl = 0; ntl < 4; ++ntl) acc[m][ntl] = 0.0f;

  #pragma unroll
  for (int ks = 0; ks < 4; ++ks) {
    int kb = ks * 32 + lk * 8;
    #pragma unroll
    for (int m = 0; m < 4; ++m) {
      bf16x8 a = *(const bf16x8*)&x[m * 16 + lr][kb];
      #pragma unroll
      for (int ntl = 0; ntl < 4; ++ntl)
        acc[m][ntl] = __builtin_amdgcn_mfma_f32_16x16x32_bf16(a, breg[ks][ntl], acc[m][ntl], 0, 0, 0);
    }
  }

  #pragma unroll
  for (int ntl = 0; ntl < 4; ++ntl) {
    int col = w * 64 + ntl * 16 + lr;
    #pragma unroll
    for (int m = 0; m < 4; ++m) {
      int rb = m * 16 + lk * 4;
      f32x4 c = acc[m][ntl];
      #pragma unroll
      for (int r = 0; r < 4; ++r) {
        int node = n0 + rb + r;
        if (node < N) nsAll[(size_t)node * 256 + col] = f2bf(c[r]);
      }
      if (col >= 128) {
        int head = (col & 127) >> 4;
        float a2v = at2[col & 127];
        float s0 = c[0] * a2v, s1 = c[1] * a2v, s2 = c[2] * a2v, s3 = c[3] * a2v;
        #pragma unroll
        for (int off = 1; off < 16; off <<= 1) {
          s0 += __shfl_xor(s0, off);
          s1 += __shfl_xor(s1, off);
          s2 += __shfl_xor(s2, off);
          s3 += __shfl_xor(s3, off);
        }
        if (lr == 0) {
          float sa[4] = {s0, s1, s2, s3};
          #pragma unroll
          for (int r = 0; r < 4; ++r) {
            int node = n0 + rb + r;
            if (node < N) c2n[(size_t)node * NH + head] = sa[r];
          }
        }
      }
    }
  }

  {
    int ei = t >> 2, q = t & 3;
    int node = n0 + ei;
    if (node < N) {
      float a0 = 0.0f, a1 = 0.0f;
      for (int kb = 0; kb < FT; kb += 8) {
        u16x8 xv8 = *(const u16x8*)&x[ei][kb];
        #pragma unroll
        for (int j = 0; j < 8; ++j) {
          float xv = bf2f(xv8[j]);
          a0 = fmaf(xv, Wa1[(kb + j) * NH + 2 * q], a0);
          a1 = fmaf(xv, Wa1[(kb + j) * NH + 2 * q + 1], a1);
        }
      }
      a1n[(size_t)node * NH + 2 * q]     = a0;
      a1n[(size_t)node * NH + 2 * q + 1] = a1;
    }
  }
}

// ---------------- CSR: fused exclusive scan (block prefix computed directly from cnt) ----------------
__global__ void k_scan(const int* __restrict__ cnt, int* __restrict__ ptr,
                       int* __restrict__ cur, int N, int E) {
  int i = blockIdx.x * 256 + threadIdx.x;
  int v = (i < N) ? cnt[i] : 0;
  int lane = threadIdx.x & 63, wv = threadIdx.x >> 6;

  // block offset: all 256 threads cooperatively sum cnt[0 .. blockIdx*256)
  __shared__ int partial[4];
  {
    int lim = blockIdx.x * 256;
    int acc = 0;
    for (int j = (int)threadIdx.x; j < lim; j += 256) acc += cnt[j];
    #pragma unroll
    for (int o = 1; o < 64; o <<= 1) acc += __shfl_xor(acc, o);
    if (lane == 0) partial[wv] = acc;
  }

  int s = v;
  #pragma unroll
  for (int o = 1; o < 64; o <<= 1) {
    int x = __shfl_up(s, o);
    if (lane >= o) s += x;
  }
  __shared__ int wsum[4];
  if (lane == 63) wsum[wv] = s;
  __syncthreads();
  int bOff = partial[0] + partial[1] + partial[2] + partial[3];
  int add = 0;
  for (int k = 0; k < wv; ++k) add += wsum[k];
  int exc = bOff + add + s - v;
  if (i < N) { ptr[i] = exc; cur[i] = exc; }
  if (i == 0) ptr[N] = E;
}

// ---------------- CSR: fill inverse permutation pos + sorted src ----------------
__global__ void k_fill(const int* __restrict__ dst, const int* __restrict__ src,
                       int* __restrict__ cur, int* __restrict__ pos,
                       int* __restrict__ srcS, int E) {
  int e = blockIdx.x * 256 + threadIdx.x;
  if (e < E) {
    int p = atomicAdd(&cur[dst[e]], 1);
    pos[e] = p;
    srcS[p] = src[e];
  }
}

// ---------------- edge GEMM: 4 tiles/block, scatter-store eps[pos[e]] ----------------
__global__ __launch_bounds__(256) void k_edge_mfma(
    const float* __restrict__ eft, const ushort* __restrict__ Wt1,
    const int* __restrict__ pos, ushort* __restrict__ eps, int E)
{
  __shared__ ushort x[64][136];
  __shared__ ushort y[64][136];

  const int t = threadIdx.x;
  const int w  = t >> 6;
  const int l  = t & 63;
  const int lr = l & 15;
  const int lk = l >> 4;
  const int erow = t >> 4;
  const int ccol = (t & 15) * 8;

  bf16x8 breg[4][2];
  const ushort* wb = Wt1 + ((size_t)(w * 32 + lr) * 128 + lk * 8);
  #pragma unroll
  for (int ks = 0; ks < 4; ++ks) {
    breg[ks][0] = *(const bf16x8*)(wb + ks * 32);
    breg[ks][1] = *(const bf16x8*)(wb + 16 * 128 + ks * 32);
  }

  #pragma unroll
  for (int tile = 0; tile < 4; ++tile) {
    const int e0 = (blockIdx.x * 4 + tile) * 64;

    int pe[4];
    #pragma unroll
    for (int r = 0; r < 4; ++r) {
      int e = e0 + r * 16 + erow;
      pe[r] = (e < E) ? pos[e] : -1;
    }

    #pragma unroll
    for (int r = 0; r < 4; ++r) {
      int ei = r * 16 + erow;
      const float* ef = eft + (size_t)min(e0 + ei, E - 1) * FT + ccol;
      float4 u = *(const float4*)ef;
      float4 v = *(const float4*)(ef + 4);
      u16x8 pk;
      pk[0] = f2bf(u.x); pk[1] = f2bf(u.y); pk[2] = f2bf(u.z); pk[3] = f2bf(u.w);
      pk[4] = f2bf(v.x); pk[5] = f2bf(v.y); pk[6] = f2bf(v.z); pk[7] = f2bf(v.w);
      *(u16x8*)&x[ei][ccol] = pk;
    }
    __syncthreads();

    f32x4 acc[4][2];
    #pragma unroll
    for (int m = 0; m < 4; ++m) { acc[m][0] = 0.0f; acc[m][1] = 0.0f; }

    #pragma unroll
    for (int ks = 0; ks < 4; ++ks) {
      int kb = ks * 32 + lk * 8;
      #pragma unroll
      for (int m = 0; m < 4; ++m) {
        bf16x8 a = *(const bf16x8*)&x[m * 16 + lr][kb];
        acc[m][0] = __builtin_amdgcn_mfma_f32_16x16x32_bf16(a, breg[ks][0], acc[m][0], 0, 0, 0);
        acc[m][1] = __builtin_amdgcn_mfma_f32_16x16x32_bf16(a, breg[ks][1], acc[m][1], 0, 0, 0);
      }
    }

    #pragma unroll
    for (int ntl = 0; ntl < 2; ++ntl) {
      int col = w * 32 + ntl * 16 + lr;
      #pragma unroll
      for (int m = 0; m < 4; ++m) {
        int rb = m * 16 + lk * 4;
        f32x4 c = acc[m][ntl];
        y[rb + 0][col] = f2bf(c[0]);
        y[rb + 1][col] = f2bf(c[1]);
        y[rb + 2][col] = f2bf(c[2]);
        y[rb + 3][col] = f2bf(c[3]);
      }
    }
    __syncthreads();

    #pragma unroll
    for (int r = 0; r < 4; ++r) {
      int ei = r * 16 + erow;
      if (pe[r] >= 0) {
        u16x8 vv = *(const u16x8*)&y[ei][ccol];
        *(u16x8*)&eps[(size_t)pe[r] * FT + ccol] = vv;
      }
    }
  }
}

// ---------------- aggregate: wave-per-node, 4x-unrolled online softmax ----------------
__global__ __launch_bounds__(256) void k_aggregate(
    const ushort* __restrict__ eps, const ushort* __restrict__ nsAll,
    const float* __restrict__ a1n, const float* __restrict__ c2n,
    const float* __restrict__ cb, const int* __restrict__ ptr,
    const int* __restrict__ srcS, const float* __restrict__ at2,
    const float* __restrict__ bp, const float* __restrict__ nft,
    float* __restrict__ out, int N)
{
  int wid = (blockIdx.x * 256 + threadIdx.x) >> 6;
  int l = threadIdx.x & 63;
  if (wid >= N) return;
  int beg = ptr[wid], end = ptr[wid + 1];
  int hh = l >> 3;
  float at0 = at2[l * 2], at1 = at2[l * 2 + 1];
  float c2b = c2n[(size_t)wid * NH + hh] + cb[hh];

  float m = -INFINITY, s = 0.0f, a0 = 0.0f, a1 = 0.0f;
  int i = beg;

  for (; i + 3 < end; i += 4) {
    int se0 = srcS[i],     se1 = srcS[i + 1];
    int se2 = srcS[i + 2], se3 = srcS[i + 3];
    unsigned pe0 = *(const unsigned*)&eps[(size_t)i * FT + l * 2];
    unsigned pe1 = *(const unsigned*)&eps[(size_t)(i + 1) * FT + l * 2];
    unsigned pe2 = *(const unsigned*)&eps[(size_t)(i + 2) * FT + l * 2];
    unsigned pe3 = *(const unsigned*)&eps[(size_t)(i + 3) * FT + l * 2];
    unsigned pn0 = *(const unsigned*)&nsAll[(size_t)se0 * 256 + l * 2];
    unsigned pn1 = *(const unsigned*)&nsAll[(size_t)se1 * 256 + l * 2];
    unsigned pn2 = *(const unsigned*)&nsAll[(size_t)se2 * 256 + l * 2];
    unsigned pn3 = *(const unsigned*)&nsAll[(size_t)se3 * 256 + l * 2];
    float p00 = __uint_as_float(pe0 << 16)         + __uint_as_float(pn0 << 16);
    float p01 = __uint_as_float(pe0 & 0xFFFF0000u) + __uint_as_float(pn0 & 0xFFFF0000u);
    float p10 = __uint_as_float(pe1 << 16)         + __uint_as_float(pn1 << 16);
    float p11 = __uint_as_float(pe1 & 0xFFFF0000u) + __uint_as_float(pn1 & 0xFFFF0000u);
    float p20 = __uint_as_float(pe2 << 16)         + __uint_as_float(pn2 << 16);
    float p21 = __uint_as_float(pe2 & 0xFFFF0000u) + __uint_as_float(pn2 & 0xFFFF0000u);
    float p30 = __uint_as_float(pe3 << 16)         + __uint_as_float(pn3 << 16);
    float p31 = __uint_as_float(pe3 & 0xFFFF0000u) + __uint_as_float(pn3 & 0xFFFF0000u);
    float ce0 = p00 * at0 + p01 * at1;
    float ce1 = p10 * at0 + p11 * at1;
    float ce2 = p20 * at0 + p21 * at1;
    float ce3 = p30 * at0 + p31 * at1;
    ce0 += __shfl_xor(ce0, 1); ce1 += __shfl_xor(ce1, 1);
    ce2 += __shfl_xor(ce2, 1); ce3 += __shfl_xor(ce3, 1);
    ce0 += __shfl_xor(ce0, 2); ce1 += __shfl_xor(ce1, 2);
    ce2 += __shfl_xor(ce2, 2); ce3 += __shfl_xor(ce3, 2);
    ce0 += __shfl_xor(ce0, 4); ce1 += __shfl_xor(ce1, 4);
    ce2 += __shfl_xor(ce2, 4); ce3 += __shfl_xor(ce3, 4);
    float lin0 = a1n[(size_t)se0 * NH + hh] + ce0 + c2b;
    float lin1 = a1n[(size_t)se1 * NH + hh] + ce1 + c2b;
    float lin2 = a1n[(size_t)se2 * NH + hh] + ce2 + c2b;
    float lin3 = a1n[(size_t)se3 * NH + hh] + ce3 + c2b;
    float lv0 = lin0 > 0.0f ? lin0 : 0.01f * lin0;
    float lv1 = lin1 > 0.0f ? lin1 : 0.01f * lin1;
    float lv2 = lin2 > 0.0f ? lin2 : 0.01f * lin2;
    float lv3 = lin3 > 0.0f ? lin3 : 0.01f * lin3;
    float mn = fmaxf(fmaxf(m, fmaxf(lv0, lv1)), fmaxf(lv2, lv3));
    float corr = __expf(m - mn);
    float e0 = __expf(lv0 - mn);
    float e1 = __expf(lv1 - mn);
    float e2 = __expf(lv2 - mn);
    float e3 = __expf(lv3 - mn);
    s  = s  * corr + e0 + e1 + e2 + e3;
    a0 = a0 * corr + e0 * p00 + e1 * p10 + e2 * p20 + e3 * p30;
    a1 = a1 * corr + e0 * p01 + e1 * p11 + e2 * p21 + e3 * p31;
    m = mn;
  }
  for (; i + 1 < end; i += 2) {
    int se0 = srcS[i];
    int se1 = srcS[i + 1];
    unsigned pe0 = *(const unsigned*)&eps[(size_t)i * FT + l * 2];
    unsigned pe1 = *(const unsigned*)&eps[(size_t)(i + 1) * FT + l * 2];
    unsigned pn0 = *(const unsigned*)&nsAll[(size_t)se0 * 256 + l * 2];
    unsigned pn1 = *(const unsigned*)&nsAll[(size_t)se1 * 256 + l * 2];
    float p00 = __uint_as_float(pe0 << 16)         + __uint_as_float(pn0 << 16);
    float p01 = __uint_as_float(pe0 & 0xFFFF0000u) + __uint_as_float(pn0 & 0xFFFF0000u);
    float p10 = __uint_as_float(pe1 << 16)         + __uint_as_float(pn1 << 16);
    float p11 = __uint_as_float(pe1 & 0xFFFF0000u) + __uint_as_float(pn1 & 0xFFFF0000u);
    float ce0 = p00 * at0 + p01 * at1;
    float ce1 = p10 * at0 + p11 * at1;
    ce0 += __shfl_xor(ce0, 1); ce1 += __shfl_xor(ce1, 1);
    ce0 += __shfl_xor(ce0, 2); ce1 += __shfl_xor(ce1, 2);
    ce0 += __shfl_xor(ce0, 4); ce1 += __shfl_xor(ce1, 4);
    float lin0 = a1n[(size_t)se0 * NH + hh] + ce0 + c2b;
    float lin1 = a1n[(size_t)se1 * NH + hh] + ce1 + c2b;
    float lv0 = lin0 > 0.0f ? lin0 : 0.01f * lin0;
    float lv1 = lin1 > 0.0f ? lin1 : 0.01f * lin1;
    float mn = fmaxf(m, fmaxf(lv0, lv1));
    float corr = __expf(m - mn);
    float e0 = __expf(lv0 - mn);
    float e1 = __expf(lv1 - mn);
    s  = s  * corr + e0 + e1;
    a0 = a0 * corr + e0 * p00 + e1 * p10;
    a1 = a1 * corr + e0 * p01 + e1 * p11;
    m = mn;
  }
  if (i < end) {
    int se = srcS[i];
    unsigned pe = *(const unsigned*)&eps[(size_t)i * FT + l * 2];
    unsigned pn = *(const unsigned*)&nsAll[(size_t)se * 256 + l * 2];
    float p0 = __uint_as_float(pe << 16)         + __uint_as_float(pn << 16);
    float p1 = __uint_as_float(pe & 0xFFFF0000u) + __uint_as_float(pn & 0xFFFF0000u);
    float ce = p0 * at0 + p1 * at1;
    ce += __shfl_xor(ce, 1);
    ce += __shfl_xor(ce, 2);
    ce += __shfl_xor(ce, 4);
    float lin = a1n[(size_t)se * NH + hh] + ce + c2b;
    float lv = lin > 0.0f ? lin : 0.01f * lin;
    float mn = fmaxf(m, lv);
    float corr = __expf(m - mn);
    float ev   = __expf(lv - mn);
    s  = s  * corr + ev;
    a0 = a0 * corr + ev * p0;
    a1 = a1 * corr + ev * p1;
    m = mn;
  }

  float2 nv = *(const float2*)&nft[(size_t)wid * FT + l * 2];
  float v0, v1;
  if (s > 0.0f) {
    float inv = 1.0f / s;
    unsigned pn2 = *(const unsigned*)&nsAll[(size_t)wid * 256 + 128 + l * 2];
    float2 bv = *(const float2*)&bp[l * 2];
    v0 = a0 * inv + __uint_as_float(pn2 << 16)         + bv.x + nv.x;
    v1 = a1 * inv + __uint_as_float(pn2 & 0xFFFF0000u) + bv.y + nv.y;
  } else {
    v0 = nv.x; v1 = nv.y;
  }
  float2 ov;
  ov.x = v0 > 0.0f ? v0 : 0.0f;
  ov.y = v1 > 0.0f ? v1 : 0.0f;
  *(float2*)&out[(size_t)wid * FT + l * 2] = ov;
}

extern "C" void kernel_launch(void* const* d_in, const int* in_sizes, int n_in,
                              void* d_out, int out_size, void* d_ws, size_t ws_size,
                              hipStream_t stream) {
  const float* nft = (const float*)d_in[0];
  const float* eft = (const float*)d_in[1];
  const float* Wp  = (const float*)d_in[2];
  const float* bp  = (const float*)d_in[3];
  const float* Wa1 = (const float*)d_in[4];
  const float* at2 = (const float*)d_in[5];
  const int*   src = (const int*)d_in[6];
  const int*   dst = (const int*)d_in[7];
  const int N = in_sizes[0] / FT;
  const int E = in_sizes[6];
  const int nb = (N + 255) / 256;
  const int nbE = (E + 255) / 256;
  const int nbN = (N + 63) / 64;

  char* ws = (char*)d_ws;
  size_t off = 0;
  ushort* eps = (ushort*)(ws + off);   off += (size_t)E * FT * sizeof(ushort);
  off = (off + 255) & ~(size_t)255;
  ushort* Wt1 = (ushort*)(ws + off);   off += (size_t)128 * 128 * sizeof(ushort);
  ushort* WtN = (ushort*)(ws + off);   off += (size_t)256 * 128 * sizeof(ushort);
  off = (off + 255) & ~(size_t)255;
  float* a1n = (float*)(ws + off);     off += (size_t)N * NH * sizeof(float);
  float* c2n = (float*)(ws + off);     off += (size_t)N * NH * sizeof(float);
  float* cb = (float*)(ws + off);      off += 256;
  ushort* nsAll = (ushort*)(ws + off); off += (size_t)N * 256 * sizeof(ushort);
  off = (off + 255) & ~(size_t)255;
  int* cnt = (int*)(ws + off);         off += (size_t)N * sizeof(int);
  int* ptr = (int*)(ws + off);         off += (size_t)(N + 1) * sizeof(int);
  int* cur = (int*)(ws + off);         off += (size_t)N * sizeof(int);
  int* pos = (int*)(ws + off);         off += (size_t)E * sizeof(int);
  int* srcS = (int*)(ws + off);        off += (size_t)E * sizeof(int);

  int setup_n = (256 * 128 > N ? 256 * 128 : N);
  k_setup<<<(setup_n + 255) / 256, 256, 0, stream>>>(Wp, bp, at2, Wt1, WtN, cb, cnt, N);

  k_combo<<<nbE + nbN, 256, 0, stream>>>(dst, cnt, E, nbE,
                                         nft, WtN, at2, Wa1, nsAll, c2n, a1n, N);

  k_scan<<<nb, 256, 0, stream>>>(cnt, ptr, cur, N, E);
  k_fill<<<(E + 255) / 256, 256, 0, stream>>>(dst, src, cur, pos, srcS, E);

  k_edge_mfma<<<(E + 255) / 256, 256, 0, stream>>>(eft, Wt1, pos, eps, E);

  k_aggregate<<<(N * 64 + 255) / 256, 256, 0, stream>>>(eps, nsAll, a1n, c2n, cb,
                                                        ptr, srcS, at2, bp,
                                                        nft, (float*)d_out, N);
}

// Round 20
// 143.219 us; speedup vs baseline: 1.0570x; 1.0570x over previous
//
#include <hip/hip_runtime.h>
#include <hip/hip_bf16.h>

#define FT 128
#define NH 8

typedef short bf16x8 __attribute__((ext_vector_type(8)));
typedef ushort u16x8 __attribute__((ext_vector_type(8)));
typedef float f32x4 __attribute__((ext_vector_type(4)));

__device__ __forceinline__ ushort f2bf(float f) {
  __hip_bfloat16 h = __float2bfloat16(f);
  return *reinterpret_cast<ushort*>(&h);
}
__device__ __forceinline__ float bf2f(ushort u) {
  return __uint_as_float(((unsigned)u) << 16);
}

// ---------------- setup: zero cnt + build Wt1/WtN (bf16 B-layout) + cb ----------------
__global__ void k_setup(const float* __restrict__ Wp, const float* __restrict__ bp,
                        const float* __restrict__ at2, ushort* __restrict__ Wt1,
                        ushort* __restrict__ WtN, float* __restrict__ cb,
                        int* __restrict__ cnt, int N) {
  int i = blockIdx.x * 256 + threadIdx.x;
  if (i < N) cnt[i] = 0;
  if (i < 128 * 128) {
    int c = i >> 7, k = i & 127;
    Wt1[i] = f2bf(Wp[(size_t)(128 + k) * 128 + c]);
  }
  if (i < 256 * 128) {
    int c = i >> 7, k = i & 127;
    float v = (c < 128) ? Wp[(size_t)k * 128 + c]
                        : Wp[(size_t)(256 + k) * 128 + (c - 128)];
    WtN[i] = f2bf(v);
  }
  if (i < NH) {
    float s = 0.0f;
    #pragma unroll
    for (int j = 0; j < 16; ++j) s += bp[i * 16 + j] * at2[i * 16 + j];
    cb[i] = s;
  }
}

// ---------------- COMBO: blocks [0,nbE) = histogram; blocks [nbE,..) = node GEMM ----------------
__global__ __launch_bounds__(256) void k_combo(
    const int* __restrict__ dst, int* __restrict__ cnt, int E, int nbE,
    const float* __restrict__ nft, const ushort* __restrict__ WtN,
    const float* __restrict__ at2, const float* __restrict__ Wa1,
    ushort* __restrict__ nsAll, float* __restrict__ c2n,
    float* __restrict__ a1n, int N)
{
  __shared__ ushort x[64][136];
  const int t = threadIdx.x;

  if ((int)blockIdx.x < nbE) {
    // ---- histogram part ----
    int e = blockIdx.x * 256 + t;
    if (e < E) atomicAdd(&cnt[dst[e]], 1);
    return;
  }

  // ---- node GEMM part ----
  const int n0 = (blockIdx.x - nbE) * 64;

  #pragma unroll
  for (int r = 0; r < 4; ++r) {
    int idx = r * 2048 + t * 8;
    int ei = idx >> 7, c = idx & 127;
    const float* xr = nft + (size_t)min(n0 + ei, N - 1) * FT + c;
    float4 u = *(const float4*)xr;
    float4 v = *(const float4*)(xr + 4);
    u16x8 pk;
    pk[0] = f2bf(u.x); pk[1] = f2bf(u.y); pk[2] = f2bf(u.z); pk[3] = f2bf(u.w);
    pk[4] = f2bf(v.x); pk[5] = f2bf(v.y); pk[6] = f2bf(v.z); pk[7] = f2bf(v.w);
    *(u16x8*)&x[ei][c] = pk;
  }
  __syncthreads();

  const int w  = t >> 6;
  const int l  = t & 63;
  const int lr = l & 15;
  const int lk = l >> 4;

  bf16x8 breg[4][4];
  const ushort* wb = WtN + ((size_t)(w * 64 + lr) * 128 + lk * 8);
  #pragma unroll
  for (int ntl = 0; ntl < 4; ++ntl)
    #pragma unroll
    for (int ks = 0; ks < 4; ++ks)
      breg[ks][ntl] = *(const bf16x8*)(wb + (size_t)ntl * 16 * 128 + ks * 32);

  f32x4 acc[4][4];
  #pragma unroll
  for (int m = 0; m < 4; ++m)
    #pragma unroll
    for (int ntl = 0; ntl < 4; ++ntl) acc[m][ntl] = 0.0f;

  #pragma unroll
  for (int ks = 0; ks < 4; ++ks) {
    int kb = ks * 32 + lk * 8;
    #pragma unroll
    for (int m = 0; m < 4; ++m) {
      bf16x8 a = *(const bf16x8*)&x[m * 16 + lr][kb];
      #pragma unroll
      for (int ntl = 0; ntl < 4; ++ntl)
        acc[m][ntl] = __builtin_amdgcn_mfma_f32_16x16x32_bf16(a, breg[ks][ntl], acc[m][ntl], 0, 0, 0);
    }
  }

  #pragma unroll
  for (int ntl = 0; ntl < 4; ++ntl) {
    int col = w * 64 + ntl * 16 + lr;
    #pragma unroll
    for (int m = 0; m < 4; ++m) {
      int rb = m * 16 + lk * 4;
      f32x4 c = acc[m][ntl];
      #pragma unroll
      for (int r = 0; r < 4; ++r) {
        int node = n0 + rb + r;
        if (node < N) nsAll[(size_t)node * 256 + col] = f2bf(c[r]);
      }
      if (col >= 128) {
        int head = (col & 127) >> 4;
        float a2v = at2[col & 127];
        float s0 = c[0] * a2v, s1 = c[1] * a2v, s2 = c[2] * a2v, s3 = c[3] * a2v;
        #pragma unroll
        for (int off = 1; off < 16; off <<= 1) {
          s0 += __shfl_xor(s0, off);
          s1 += __shfl_xor(s1, off);
          s2 += __shfl_xor(s2, off);
          s3 += __shfl_xor(s3, off);
        }
        if (lr == 0) {
          float sa[4] = {s0, s1, s2, s3};
          #pragma unroll
          for (int r = 0; r < 4; ++r) {
            int node = n0 + rb + r;
            if (node < N) c2n[(size_t)node * NH + head] = sa[r];
          }
        }
      }
    }
  }

  {
    int ei = t >> 2, q = t & 3;
    int node = n0 + ei;
    if (node < N) {
      float a0 = 0.0f, a1 = 0.0f;
      for (int kb = 0; kb < FT; kb += 8) {
        u16x8 xv8 = *(const u16x8*)&x[ei][kb];
        #pragma unroll
        for (int j = 0; j < 8; ++j) {
          float xv = bf2f(xv8[j]);
          a0 = fmaf(xv, Wa1[(kb + j) * NH + 2 * q], a0);
          a1 = fmaf(xv, Wa1[(kb + j) * NH + 2 * q + 1], a1);
        }
      }
      a1n[(size_t)node * NH + 2 * q]     = a0;
      a1n[(size_t)node * NH + 2 * q + 1] = a1;
    }
  }
}

// ---------------- CSR: block sums ----------------
__global__ void k_scan1(const int* __restrict__ cnt, int* __restrict__ bsum, int N) {
  int i = blockIdx.x * 256 + threadIdx.x;
  int v = (i < N) ? cnt[i] : 0;
  #pragma unroll
  for (int o = 1; o < 64; o <<= 1) v += __shfl_xor(v, o);
  __shared__ int ws[4];
  if ((threadIdx.x & 63) == 0) ws[threadIdx.x >> 6] = v;
  __syncthreads();
  if (threadIdx.x == 0) bsum[blockIdx.x] = ws[0] + ws[1] + ws[2] + ws[3];
}

// ---------------- CSR: per-element exclusive scan; block computes own bsum prefix ----------------
__global__ void k_scan3(const int* __restrict__ cnt, const int* __restrict__ bsum,
                        int* __restrict__ ptr, int* __restrict__ cur, int N, int E) {
  int i = blockIdx.x * 256 + threadIdx.x;
  int v = (i < N) ? cnt[i] : 0;
  int lane = threadIdx.x & 63, wv = threadIdx.x >> 6;
  __shared__ int bOff;
  if (threadIdx.x < 64) {
    int acc = 0;
    for (int b = lane; b < blockIdx.x; b += 64) acc += bsum[b];
    #pragma unroll
    for (int o = 1; o < 64; o <<= 1) acc += __shfl_xor(acc, o);
    if (lane == 0) bOff = acc;
  }
  int s = v;
  #pragma unroll
  for (int o = 1; o < 64; o <<= 1) {
    int x = __shfl_up(s, o);
    if (lane >= o) s += x;
  }
  __shared__ int wsum[4];
  if (lane == 63) wsum[wv] = s;
  __syncthreads();
  int add = 0;
  for (int k = 0; k < wv; ++k) add += wsum[k];
  int exc = bOff + add + s - v;
  if (i < N) { ptr[i] = exc; cur[i] = exc; }
  if (i == 0) ptr[N] = E;
}

// ---------------- CSR: fill inverse permutation pos + sorted src ----------------
__global__ void k_fill(const int* __restrict__ dst, const int* __restrict__ src,
                       int* __restrict__ cur, int* __restrict__ pos,
                       int* __restrict__ srcS, int E) {
  int e = blockIdx.x * 256 + threadIdx.x;
  if (e < E) {
    int p = atomicAdd(&cur[dst[e]], 1);
    pos[e] = p;
    srcS[p] = src[e];
  }
}

// ---------------- edge GEMM: 4 tiles/block, scatter-store eps[pos[e]] ----------------
__global__ __launch_bounds__(256) void k_edge_mfma(
    const float* __restrict__ eft, const ushort* __restrict__ Wt1,
    const int* __restrict__ pos, ushort* __restrict__ eps, int E)
{
  __shared__ ushort x[64][136];
  __shared__ ushort y[64][136];

  const int t = threadIdx.x;
  const int w  = t >> 6;
  const int l  = t & 63;
  const int lr = l & 15;
  const int lk = l >> 4;
  const int erow = t >> 4;
  const int ccol = (t & 15) * 8;

  bf16x8 breg[4][2];
  const ushort* wb = Wt1 + ((size_t)(w * 32 + lr) * 128 + lk * 8);
  #pragma unroll
  for (int ks = 0; ks < 4; ++ks) {
    breg[ks][0] = *(const bf16x8*)(wb + ks * 32);
    breg[ks][1] = *(const bf16x8*)(wb + 16 * 128 + ks * 32);
  }

  #pragma unroll
  for (int tile = 0; tile < 4; ++tile) {
    const int e0 = (blockIdx.x * 4 + tile) * 64;

    int pe[4];
    #pragma unroll
    for (int r = 0; r < 4; ++r) {
      int e = e0 + r * 16 + erow;
      pe[r] = (e < E) ? pos[e] : -1;
    }

    #pragma unroll
    for (int r = 0; r < 4; ++r) {
      int ei = r * 16 + erow;
      const float* ef = eft + (size_t)min(e0 + ei, E - 1) * FT + ccol;
      float4 u = *(const float4*)ef;
      float4 v = *(const float4*)(ef + 4);
      u16x8 pk;
      pk[0] = f2bf(u.x); pk[1] = f2bf(u.y); pk[2] = f2bf(u.z); pk[3] = f2bf(u.w);
      pk[4] = f2bf(v.x); pk[5] = f2bf(v.y); pk[6] = f2bf(v.z); pk[7] = f2bf(v.w);
      *(u16x8*)&x[ei][ccol] = pk;
    }
    __syncthreads();

    f32x4 acc[4][2];
    #pragma unroll
    for (int m = 0; m < 4; ++m) { acc[m][0] = 0.0f; acc[m][1] = 0.0f; }

    #pragma unroll
    for (int ks = 0; ks < 4; ++ks) {
      int kb = ks * 32 + lk * 8;
      #pragma unroll
      for (int m = 0; m < 4; ++m) {
        bf16x8 a = *(const bf16x8*)&x[m * 16 + lr][kb];
        acc[m][0] = __builtin_amdgcn_mfma_f32_16x16x32_bf16(a, breg[ks][0], acc[m][0], 0, 0, 0);
        acc[m][1] = __builtin_amdgcn_mfma_f32_16x16x32_bf16(a, breg[ks][1], acc[m][1], 0, 0, 0);
      }
    }

    #pragma unroll
    for (int ntl = 0; ntl < 2; ++ntl) {
      int col = w * 32 + ntl * 16 + lr;
      #pragma unroll
      for (int m = 0; m < 4; ++m) {
        int rb = m * 16 + lk * 4;
        f32x4 c = acc[m][ntl];
        y[rb + 0][col] = f2bf(c[0]);
        y[rb + 1][col] = f2bf(c[1]);
        y[rb + 2][col] = f2bf(c[2]);
        y[rb + 3][col] = f2bf(c[3]);
      }
    }
    __syncthreads();

    #pragma unroll
    for (int r = 0; r < 4; ++r) {
      int ei = r * 16 + erow;
      if (pe[r] >= 0) {
        u16x8 vv = *(const u16x8*)&y[ei][ccol];
        *(u16x8*)&eps[(size_t)pe[r] * FT + ccol] = vv;
      }
    }
  }
}

// ---------------- aggregate: wave-per-node, 4x-unrolled online softmax ----------------
__global__ __launch_bounds__(256) void k_aggregate(
    const ushort* __restrict__ eps, const ushort* __restrict__ nsAll,
    const float* __restrict__ a1n, const float* __restrict__ c2n,
    const float* __restrict__ cb, const int* __restrict__ ptr,
    const int* __restrict__ srcS, const float* __restrict__ at2,
    const float* __restrict__ bp, const float* __restrict__ nft,
    float* __restrict__ out, int N)
{
  int wid = (blockIdx.x * 256 + threadIdx.x) >> 6;
  int l = threadIdx.x & 63;
  if (wid >= N) return;
  int beg = ptr[wid], end = ptr[wid + 1];
  int hh = l >> 3;
  float at0 = at2[l * 2], at1 = at2[l * 2 + 1];
  float c2b = c2n[(size_t)wid * NH + hh] + cb[hh];

  float m = -INFINITY, s = 0.0f, a0 = 0.0f, a1 = 0.0f;
  int i = beg;

  for (; i + 3 < end; i += 4) {
    int se0 = srcS[i],     se1 = srcS[i + 1];
    int se2 = srcS[i + 2], se3 = srcS[i + 3];
    unsigned pe0 = *(const unsigned*)&eps[(size_t)i * FT + l * 2];
    unsigned pe1 = *(const unsigned*)&eps[(size_t)(i + 1) * FT + l * 2];
    unsigned pe2 = *(const unsigned*)&eps[(size_t)(i + 2) * FT + l * 2];
    unsigned pe3 = *(const unsigned*)&eps[(size_t)(i + 3) * FT + l * 2];
    unsigned pn0 = *(const unsigned*)&nsAll[(size_t)se0 * 256 + l * 2];
    unsigned pn1 = *(const unsigned*)&nsAll[(size_t)se1 * 256 + l * 2];
    unsigned pn2 = *(const unsigned*)&nsAll[(size_t)se2 * 256 + l * 2];
    unsigned pn3 = *(const unsigned*)&nsAll[(size_t)se3 * 256 + l * 2];
    float p00 = __uint_as_float(pe0 << 16)         + __uint_as_float(pn0 << 16);
    float p01 = __uint_as_float(pe0 & 0xFFFF0000u) + __uint_as_float(pn0 & 0xFFFF0000u);
    float p10 = __uint_as_float(pe1 << 16)         + __uint_as_float(pn1 << 16);
    float p11 = __uint_as_float(pe1 & 0xFFFF0000u) + __uint_as_float(pn1 & 0xFFFF0000u);
    float p20 = __uint_as_float(pe2 << 16)         + __uint_as_float(pn2 << 16);
    float p21 = __uint_as_float(pe2 & 0xFFFF0000u) + __uint_as_float(pn2 & 0xFFFF0000u);
    float p30 = __uint_as_float(pe3 << 16)         + __uint_as_float(pn3 << 16);
    float p31 = __uint_as_float(pe3 & 0xFFFF0000u) + __uint_as_float(pn3 & 0xFFFF0000u);
    float ce0 = p00 * at0 + p01 * at1;
    float ce1 = p10 * at0 + p11 * at1;
    float ce2 = p20 * at0 + p21 * at1;
    float ce3 = p30 * at0 + p31 * at1;
    ce0 += __shfl_xor(ce0, 1); ce1 += __shfl_xor(ce1, 1);
    ce2 += __shfl_xor(ce2, 1); ce3 += __shfl_xor(ce3, 1);
    ce0 += __shfl_xor(ce0, 2); ce1 += __shfl_xor(ce1, 2);
    ce2 += __shfl_xor(ce2, 2); ce3 += __shfl_xor(ce3, 2);
    ce0 += __shfl_xor(ce0, 4); ce1 += __shfl_xor(ce1, 4);
    ce2 += __shfl_xor(ce2, 4); ce3 += __shfl_xor(ce3, 4);
    float lin0 = a1n[(size_t)se0 * NH + hh] + ce0 + c2b;
    float lin1 = a1n[(size_t)se1 * NH + hh] + ce1 + c2b;
    float lin2 = a1n[(size_t)se2 * NH + hh] + ce2 + c2b;
    float lin3 = a1n[(size_t)se3 * NH + hh] + ce3 + c2b;
    float lv0 = lin0 > 0.0f ? lin0 : 0.01f * lin0;
    float lv1 = lin1 > 0.0f ? lin1 : 0.01f * lin1;
    float lv2 = lin2 > 0.0f ? lin2 : 0.01f * lin2;
    float lv3 = lin3 > 0.0f ? lin3 : 0.01f * lin3;
    float mn = fmaxf(fmaxf(m, fmaxf(lv0, lv1)), fmaxf(lv2, lv3));
    float corr = __expf(m - mn);
    float e0 = __expf(lv0 - mn);
    float e1 = __expf(lv1 - mn);
    float e2 = __expf(lv2 - mn);
    float e3 = __expf(lv3 - mn);
    s  = s  * corr + e0 + e1 + e2 + e3;
    a0 = a0 * corr + e0 * p00 + e1 * p10 + e2 * p20 + e3 * p30;
    a1 = a1 * corr + e0 * p01 + e1 * p11 + e2 * p21 + e3 * p31;
    m = mn;
  }
  for (; i + 1 < end; i += 2) {
    int se0 = srcS[i];
    int se1 = srcS[i + 1];
    unsigned pe0 = *(const unsigned*)&eps[(size_t)i * FT + l * 2];
    unsigned pe1 = *(const unsigned*)&eps[(size_t)(i + 1) * FT + l * 2];
    unsigned pn0 = *(const unsigned*)&nsAll[(size_t)se0 * 256 + l * 2];
    unsigned pn1 = *(const unsigned*)&nsAll[(size_t)se1 * 256 + l * 2];
    float p00 = __uint_as_float(pe0 << 16)         + __uint_as_float(pn0 << 16);
    float p01 = __uint_as_float(pe0 & 0xFFFF0000u) + __uint_as_float(pn0 & 0xFFFF0000u);
    float p10 = __uint_as_float(pe1 << 16)         + __uint_as_float(pn1 << 16);
    float p11 = __uint_as_float(pe1 & 0xFFFF0000u) + __uint_as_float(pn1 & 0xFFFF0000u);
    float ce0 = p00 * at0 + p01 * at1;
    float ce1 = p10 * at0 + p11 * at1;
    ce0 += __shfl_xor(ce0, 1); ce1 += __shfl_xor(ce1, 1);
    ce0 += __shfl_xor(ce0, 2); ce1 += __shfl_xor(ce1, 2);
    ce0 += __shfl_xor(ce0, 4); ce1 += __shfl_xor(ce1, 4);
    float lin0 = a1n[(size_t)se0 * NH + hh] + ce0 + c2b;
    float lin1 = a1n[(size_t)se1 * NH + hh] + ce1 + c2b;
    float lv0 = lin0 > 0.0f ? lin0 : 0.01f * lin0;
    float lv1 = lin1 > 0.0f ? lin1 : 0.01f * lin1;
    float mn = fmaxf(m, fmaxf(lv0, lv1));
    float corr = __expf(m - mn);
    float e0 = __expf(lv0 - mn);
    float e1 = __expf(lv1 - mn);
    s  = s  * corr + e0 + e1;
    a0 = a0 * corr + e0 * p00 + e1 * p10;
    a1 = a1 * corr + e0 * p01 + e1 * p11;
    m = mn;
  }
  if (i < end) {
    int se = srcS[i];
    unsigned pe = *(const unsigned*)&eps[(size_t)i * FT + l * 2];
    unsigned pn = *(const unsigned*)&nsAll[(size_t)se * 256 + l * 2];
    float p0 = __uint_as_float(pe << 16)         + __uint_as_float(pn << 16);
    float p1 = __uint_as_float(pe & 0xFFFF0000u) + __uint_as_float(pn & 0xFFFF0000u);
    float ce = p0 * at0 + p1 * at1;
    ce += __shfl_xor(ce, 1);
    ce += __shfl_xor(ce, 2);
    ce += __shfl_xor(ce, 4);
    float lin = a1n[(size_t)se * NH + hh] + ce + c2b;
    float lv = lin > 0.0f ? lin : 0.01f * lin;
    float mn = fmaxf(m, lv);
    float corr = __expf(m - mn);
    float ev   = __expf(lv - mn);
    s  = s  * corr + ev;
    a0 = a0 * corr + ev * p0;
    a1 = a1 * corr + ev * p1;
    m = mn;
  }

  float2 nv = *(const float2*)&nft[(size_t)wid * FT + l * 2];
  float v0, v1;
  if (s > 0.0f) {
    float inv = 1.0f / s;
    unsigned pn2 = *(const unsigned*)&nsAll[(size_t)wid * 256 + 128 + l * 2];
    float2 bv = *(const float2*)&bp[l * 2];
    v0 = a0 * inv + __uint_as_float(pn2 << 16)         + bv.x + nv.x;
    v1 = a1 * inv + __uint_as_float(pn2 & 0xFFFF0000u) + bv.y + nv.y;
  } else {
    v0 = nv.x; v1 = nv.y;
  }
  float2 ov;
  ov.x = v0 > 0.0f ? v0 : 0.0f;
  ov.y = v1 > 0.0f ? v1 : 0.0f;
  *(float2*)&out[(size_t)wid * FT + l * 2] = ov;
}

extern "C" void kernel_launch(void* const* d_in, const int* in_sizes, int n_in,
                              void* d_out, int out_size, void* d_ws, size_t ws_size,
                              hipStream_t stream) {
  const float* nft = (const float*)d_in[0];
  const float* eft = (const float*)d_in[1];
  const float* Wp  = (const float*)d_in[2];
  const float* bp  = (const float*)d_in[3];
  const float* Wa1 = (const float*)d_in[4];
  const float* at2 = (const float*)d_in[5];
  const int*   src = (const int*)d_in[6];
  const int*   dst = (const int*)d_in[7];
  const int N = in_sizes[0] / FT;
  const int E = in_sizes[6];
  const int nb = (N + 255) / 256;
  const int nbE = (E + 255) / 256;
  const int nbN = (N + 63) / 64;

  char* ws = (char*)d_ws;
  size_t off = 0;
  ushort* eps = (ushort*)(ws + off);   off += (size_t)E * FT * sizeof(ushort);
  off = (off + 255) & ~(size_t)255;
  ushort* Wt1 = (ushort*)(ws + off);   off += (size_t)128 * 128 * sizeof(ushort);
  ushort* WtN = (ushort*)(ws + off);   off += (size_t)256 * 128 * sizeof(ushort);
  off = (off + 255) & ~(size_t)255;
  float* a1n = (float*)(ws + off);     off += (size_t)N * NH * sizeof(float);
  float* c2n = (float*)(ws + off);     off += (size_t)N * NH * sizeof(float);
  float* cb = (float*)(ws + off);      off += 256;
  ushort* nsAll = (ushort*)(ws + off); off += (size_t)N * 256 * sizeof(ushort);
  off = (off + 255) & ~(size_t)255;
  int* cnt = (int*)(ws + off);         off += (size_t)N * sizeof(int);
  int* ptr = (int*)(ws + off);         off += (size_t)(N + 1) * sizeof(int);
  int* cur = (int*)(ws + off);         off += (size_t)N * sizeof(int);
  int* bsum = (int*)(ws + off);        off += (size_t)nb * sizeof(int);
  int* pos = (int*)(ws + off);         off += (size_t)E * sizeof(int);
  int* srcS = (int*)(ws + off);        off += (size_t)E * sizeof(int);

  int setup_n = (256 * 128 > N ? 256 * 128 : N);
  k_setup<<<(setup_n + 255) / 256, 256, 0, stream>>>(Wp, bp, at2, Wt1, WtN, cb, cnt, N);

  k_combo<<<nbE + nbN, 256, 0, stream>>>(dst, cnt, E, nbE,
                                         nft, WtN, at2, Wa1, nsAll, c2n, a1n, N);

  k_scan1<<<nb, 256, 0, stream>>>(cnt, bsum, N);
  k_scan3<<<nb, 256, 0, stream>>>(cnt, bsum, ptr, cur, N, E);
  k_fill<<<(E + 255) / 256, 256, 0, stream>>>(dst, src, cur, pos, srcS, E);

  k_edge_mfma<<<(E + 255) / 256, 256, 0, stream>>>(eft, Wt1, pos, eps, E);

  k_aggregate<<<(N * 64 + 255) / 256, 256, 0, stream>>>(eps, nsAll, a1n, c2n, cb,
                                                        ptr, srcS, at2, bp,
                                                        nft, (float*)d_out, N);
}